// Round 8
// baseline (54.635 us; speedup 1.0000x reference)
//
#include <hip/hip_runtime.h>

#define B_    64
#define C_    23
#define E_    1024
#define D_    1024
#define BOT_  128
#define BINS_ 8192
#define S_    3
#define NUMBINS (C_*BINS_)

typedef float f32x4 __attribute__((ext_vector_type(4)));

// ws layout (floats):
// [0,384)            M  : M[s*128+k]   = sum_d Wfc[s][d]      * Wb[d][k]
// [512,512+3072)     N  : N[s*1024+e]  = sum_d Wfc[s][1024+d] * We[d][e]
// [3584,3587)        c0 : c0[s]
#define WS_M   0
#define WS_N   512
#define WS_C0  3584

// grid 73: [0,64): N (e0 = bx*16, all 3 s)  [64,72): M (k0=(bx-64)*16)  72: c0
__global__ __launch_bounds__(256) void kprep(const float* __restrict__ Wb,
                                             const float* __restrict__ We,
                                             const float* __restrict__ be,
                                             const float* __restrict__ Wfc,
                                             const float* __restrict__ bfc,
                                             float* __restrict__ ws) {
    const int bx = blockIdx.x;
    const int t  = threadIdx.x;

    if (bx == 72) {                // c0
        int wave = t >> 6, lane = t & 63;
        if (wave < 3) {
            const float* w2 = Wfc + wave * 2 * D_ + D_;
            float acc = 0.f;
            #pragma unroll
            for (int j = 0; j < D_ / 64; j++) {
                int d = lane + j * 64;
                acc += w2[d] * be[d];
            }
            #pragma unroll
            for (int off = 32; off; off >>= 1) acc += __shfl_down(acc, off);
            if (lane == 0) ws[WS_C0 + wave] = acc + bfc[wave];
        }
        return;
    }

    __shared__ float wv[3072];     // 3 broadcast rows of Wfc (w1 or w2)
    __shared__ float red[256];

    const int og   = t & 15;       // output within the 16-chunk
    const int dgrp = t >> 4;       // 0..15, each owns 64 d's

    const float* src;              // matrix: src[d*ostride + obase + og]
    int ostride, obase, wofs;
    float* dst0;                   // + s*dstride
    int dstride;

    if (bx < 64) {                 // N[s][e0+og]
        int e0 = bx * 16;
        src = We; ostride = E_; obase = e0; wofs = D_;
        dst0 = ws + WS_N + e0; dstride = E_;
    } else {                       // M[s][k0+og]
        int k0 = (bx - 64) * 16;
        src = Wb; ostride = BOT_; obase = k0; wofs = 0;
        dst0 = ws + WS_M + k0; dstride = BOT_;
    }

    for (int i = t; i < 3072; i += 256) {
        int s = i >> 10, d = i & 1023;
        wv[i] = Wfc[s * 2 * D_ + wofs + d];
    }
    __syncthreads();

    const float* p  = src + (size_t)(dgrp * 64) * ostride + obase + og;
    const float* w0 = wv + dgrp * 64;
    float a0 = 0.f, a1 = 0.f, a2 = 0.f;
    #pragma unroll 8
    for (int i = 0; i < 64; i++) {
        float v = p[(size_t)i * ostride];
        a0 += w0[i] * v;
        a1 += w0[1024 + i] * v;
        a2 += w0[2048 + i] * v;
    }
    float accs[3] = {a0, a1, a2};
    for (int s = 0; s < 3; s++) {
        __syncthreads();
        red[t] = accs[s];
        #pragma unroll
        for (int off = 128; off >= 16; off >>= 1) {
            __syncthreads();
            if (t < off) red[t] += red[t + off];
        }
        if (t < 16) dst0[s * dstride + t] = red[t];
    }
}

// grid 736 (1D, XCD-chunked swizzle: 736 = 8 XCDs x 92 blocks).
// phase 0: block computes its own pel[64][3] = eos[:,c,:]·N (+c0) via the
//          padded-P partial layout (one shfl_xor(32) pre-fold) -- redundant
//          x32 per c, but eos is L2/L3-resident and the FMAs hide under the
//          already-issued batch-0 table loads. No kpe kernel, no sync.
// phase 1: per 64-row batch: coalesced 1KB/instr table reads (reg dbuf) ->
//          padded-LDS partials -> reduce -> immediately stream the batch's
//          64-b output slice (NT f32x4) while next batch's loads fly.
__global__ __launch_bounds__(256) void kmain(const float* __restrict__ table,
                                             const float* __restrict__ eos,
                                             const float* __restrict__ ws,
                                             float* __restrict__ out) {
    const int t  = threadIdx.x;
    // XCD-chunked swizzle (bijective: 736 = 8*92)
    const int d_  = blockIdx.x;
    const int g   = (d_ & 7) * 92 + (d_ >> 3);
    const int c   = g >> 5;
    const int n0  = (g & 31) * 256;

    const int w  = t >> 6;         // wave 0..3
    const int l  = t & 63;
    const int h  = l >> 5;         // row parity within pair (phase 1)
    const int kk = l & 31;         // f32x4 quad within row

    __shared__ float P[64 * 97];   // partials, padded stride 97 (conflict-free)
    __shared__ float pbl[192];     // this batch's pb[row_local*3+s]
    __shared__ float pel[192];     // pe[b*3+s] for this c

    // per-lane M coefficients: M[s][kk*4 .. kk*4+3]
    f32x4 M0 = ((const f32x4*)(ws + WS_M      ))[kk];
    f32x4 M1 = ((const f32x4*)(ws + WS_M + 128))[kk];
    f32x4 M2 = ((const f32x4*)(ws + WS_M + 256))[kk];

    const float* base = table + (size_t)(1 + c * BINS_ + n0) * BOT_ + kk * 4;

    // issue batch-0 table loads FIRST; phase-0 compute hides their latency
    f32x4 va[8], vb[8];
    #pragma unroll
    for (int i = 0; i < 8; i++) {
        int rl = (w * 8 + i) * 2 + h;
        va[i] = *(const f32x4*)(base + (size_t)rl * BOT_);
    }

    // ---- phase 0: pel for this c ----
    {
        const f32x4* Nq = (const f32x4*)(ws + WS_N);
        f32x4 nq[12];
        #pragma unroll
        for (int s = 0; s < 3; s++)
            #pragma unroll
            for (int j = 0; j < 4; j++)
                nq[s * 4 + j] = Nq[s * 256 + l + 64 * j];
        const f32x4* eq = (const f32x4*)eos;
        #pragma unroll
        for (int rr = 0; rr < 16; rr++) {
            int r = w * 16 + rr;               // b index
            size_t eb = ((size_t)r * C_ + c) * 256;
            f32x4 e0 = eq[eb + l];
            f32x4 e1 = eq[eb + l + 64];
            f32x4 e2 = eq[eb + l + 128];
            f32x4 e3 = eq[eb + l + 192];
            float p0, p1, p2;
            #pragma unroll
            for (int s = 0; s < 3; s++) {
                f32x4 a = nq[s * 4], b4 = nq[s * 4 + 1], c4 = nq[s * 4 + 2], d4 = nq[s * 4 + 3];
                float ps = e0.x * a.x + e0.y * a.y + e0.z * a.z + e0.w * a.w
                         + e1.x * b4.x + e1.y * b4.y + e1.z * b4.z + e1.w * b4.w
                         + e2.x * c4.x + e2.y * c4.y + e2.z * c4.z + e2.w * c4.w
                         + e3.x * d4.x + e3.y * d4.y + e3.z * d4.z + e3.w * d4.w;
                ps += __shfl_xor(ps, 32);
                if (s == 0) p0 = ps; else if (s == 1) p1 = ps; else p2 = ps;
            }
            if (h == 0) {
                float* pp = &P[r * 97 + kk * 3];
                pp[0] = p0; pp[1] = p1; pp[2] = p2;
            }
        }
    }
    __syncthreads();
    if (t < 192) {
        int s = t >> 6, ro = t & 63;
        const float* pr = &P[ro * 97 + s];
        float acc = 0.f;
        #pragma unroll
        for (int k = 0; k < 32; k++) acc += pr[k * 3];
        pel[ro * 3 + s] = acc + ws[WS_C0 + s];
    }
    __syncthreads();

    // ---- phase 1: 4 batches of 64 rows ----
    #pragma unroll
    for (int bb = 0; bb < 4; bb++) {
        #pragma unroll
        for (int i = 0; i < 8; i++) {
            int rl = (w * 8 + i) * 2 + h;
            f32x4 v = (bb & 1) ? vb[i] : va[i];
            float* pp = &P[rl * 97 + kk * 3];
            pp[0] = v.x * M0.x + v.y * M0.y + v.z * M0.z + v.w * M0.w;
            pp[1] = v.x * M1.x + v.y * M1.y + v.z * M1.z + v.w * M1.w;
            pp[2] = v.x * M2.x + v.y * M2.y + v.z * M2.z + v.w * M2.w;
        }
        if (bb < 3) {
            #pragma unroll
            for (int i = 0; i < 8; i++) {
                int rl = (w * 8 + i) * 2 + h;
                f32x4 ld = *(const f32x4*)(base + (size_t)((bb + 1) * 64 + rl) * BOT_);
                if (bb & 1) va[i] = ld; else vb[i] = ld;
            }
        }
        __syncthreads();
        if (t < 192) {
            int s = t >> 6, ro = t & 63;
            const float* pr = &P[ro * 97 + s];
            float acc = 0.f;
            #pragma unroll
            for (int k = 0; k < 32; k++) acc += pr[k * 3];
            pbl[ro * 3 + s] = acc;
        }
        __syncthreads();
        // stream this batch's outputs: 64 b-slices x 48 f32x4, all 256 threads
        {
            int b  = t / 48;
            int p4 = t - b * 48;
            const float* ob = out + ((size_t)c * BINS_ + n0 + bb * 64) * 3;
            #pragma unroll
            for (int j = 0; j < 12; j++) {
                f32x4 pv = *(const f32x4*)&pbl[p4 * 4];
                int s0 = p4 % 3;            // (4*p4)%3 == p4%3
                int s1 = (s0 + 1 == 3) ? 0 : s0 + 1;
                int s2 = (s1 + 1 == 3) ? 0 : s1 + 1;
                const float* pe = &pel[b * 3];
                f32x4 o;
                o.x = fmaxf(pv.x + pe[s0], 0.f);
                o.y = fmaxf(pv.y + pe[s1], 0.f);
                o.z = fmaxf(pv.z + pe[s2], 0.f);
                o.w = fmaxf(pv.w + pe[s0], 0.f);
                f32x4* dst = (f32x4*)(ob + (size_t)b * (C_ * BINS_ * 3)) + p4;
                __builtin_nontemporal_store(o, dst);
                b += 5; p4 += 16;           // q += 256 = 5*48 + 16
                if (p4 >= 48) { p4 -= 48; b += 1; }
            }
        }
    }
}

extern "C" void kernel_launch(void* const* d_in, const int* in_sizes, int n_in,
                              void* d_out, int out_size, void* d_ws, size_t ws_size,
                              hipStream_t stream) {
    const float* eos   = (const float*)d_in[0];
    const float* table = (const float*)d_in[1];
    const float* Wb    = (const float*)d_in[2];
    const float* We    = (const float*)d_in[3];
    const float* be    = (const float*)d_in[4];
    const float* Wfc   = (const float*)d_in[5];
    const float* bfc   = (const float*)d_in[6];
    float* out = (float*)d_out;
    float* ws  = (float*)d_ws;

    kprep<<<73, 256, 0, stream>>>(Wb, We, be, Wfc, bfc, ws);
    kmain<<<736, 256, 0, stream>>>(table, eos, ws, out);
}